// Round 1
// baseline (419.099 us; speedup 1.0000x reference)
//
#include <hip/hip_runtime.h>
#include <math.h>

#define N      128
#define NSQ    (N * N)          // 16384
#define VOL    (N * N * N)      // 2097152
#define NSHELL 64
#define BTOT   8
#define FPI    3.14159265358979323846f

#define PP     130              // K1 plane pitch in float2: rows 16B-aligned, col stride 4 mod 32 dwords
#define TP2    17               // K2 tile pitch in float2 (odd -> 2 mod 32 dword column stride)

// ---------------------------------------------------------------------------
// Per-lane twiddles for the wave-register 128-pt DIF FFT.
// tc/ts[0]: raw w = exp(-i*pi*l/64) for the in-lane h=64 stage.
// k=1..6 (h=32..1): role-adjusted — lo lanes ((l&h)==0) get (1,0,+1) so the
// butterfly is v+o; hi lanes get (cos,sin)(-pi*(l&(h-1))/h) and e=-1 so the
// butterfly is (o-v)*w. Same twiddle serves both registers (64 mod h == 0).
// ---------------------------------------------------------------------------
__device__ inline void mk_tw(int l, float* tc, float* ts, float* te) {
    __sincosf(-FPI * (float)l * (1.0f / 64.0f), &ts[0], &tc[0]);
#pragma unroll
    for (int k = 1; k <= 6; ++k) {
        const int h = 64 >> k;
        float s, c;
        __sincosf(-FPI * (float)(l & (h - 1)) / (float)h, &s, &c);
        const bool hi = (l & h) != 0;
        tc[k] = hi ? c : 1.0f;
        ts[k] = hi ? s : 0.0f;
        te[k] = hi ? -1.0f : 1.0f;
    }
}

// ---------------------------------------------------------------------------
// 128-point DIF (Gentleman-Sande) FFT held across one 64-lane wave.
// In:  lane l holds a[l] (v0) and a[l+64] (v1), natural order.
// Out: lane l holds bins 2*bitrev6(l) (v0) and 2*bitrev6(l)+1 (v1).
// Stage h pairs idx and idx^h; h=64 is the in-lane register pair, h=32..1 are
// shfl_xor(h). DIF leaves bin bitrev7(idx) at position idx; with idx = r*64+l
// that is 2*bitrev6(l)+r, i.e. a consecutive pair per lane.
// ---------------------------------------------------------------------------
__device__ inline void fft128(float2& v0, float2& v1,
                              const float* tc, const float* ts, const float* te) {
    {   // h = 64: in-lane, twiddle m = l
        const float dx = v0.x - v1.x, dy = v0.y - v1.y;
        v0.x += v1.x; v0.y += v1.y;
        v1.x = dx * tc[0] - dy * ts[0];
        v1.y = dx * ts[0] + dy * tc[0];
    }
#pragma unroll
    for (int k = 1; k <= 6; ++k) {
        const int h = 64 >> k;           // 32,16,8,4,2,1
        const float c = tc[k], s = ts[k], e = te[k];
        const float o0x = __shfl_xor(v0.x, h), o0y = __shfl_xor(v0.y, h);
        const float o1x = __shfl_xor(v1.x, h), o1y = __shfl_xor(v1.y, h);
        const float t0x = fmaf(e, v0.x, o0x), t0y = fmaf(e, v0.y, o0y);
        const float t1x = fmaf(e, v1.x, o1x), t1y = fmaf(e, v1.y, o1y);
        v0.x = t0x * c - t0y * s;  v0.y = t0x * s + t0y * c;
        v1.x = t1x * c - t1y * s;  v1.y = t1x * s + t1y * c;
    }
}

// ---------------------------------------------------------------------------
// Pass 1 (fused z+y FFT): one block per (batch, x). The full (y,z) plane
// lives in LDS (130 KiB). Phase 1: wave-register FFT along z per y-line,
// natural-order row write (conflict-free float4, full row coverage).
// Phase 2: FFT along y per z-column, results written straight to global in
// y-contiguous layout Z[b][x][z][y] (1 KiB coalesced stores per line).
// ---------------------------------------------------------------------------
__global__ __launch_bounds__(1024) void k_fft_zy(const float* __restrict__ ref,
                                                 const float* __restrict__ pred,
                                                 float2* __restrict__ Z, int b0) {
    __shared__ __align__(16) float2 plane[N * PP];   // 133,120 B
    const int t = threadIdx.x, l = t & 63, w = t >> 6;   // 16 waves
    const int x  = blockIdx.x & (N - 1);
    const int bl = blockIdx.x >> 7;
    float tc[7], ts[7], te[7];
    mk_tw(l, tc, ts, te);
    const int f2 = (int)(__brev((unsigned)l) >> 26) << 1;   // 2*bitrev6(l)

    const size_t inb = (size_t)(b0 + bl) * VOL + (size_t)x * NSQ;
#pragma unroll 2
    for (int k = 0; k < 8; ++k) {
        const int y = w * 8 + k;
        const float* rp = ref  + inb + (size_t)y * N;
        const float* pp = pred + inb + (size_t)y * N;
        float2 v0 = make_float2(rp[l],      pp[l]);        // Zc = ref + i*pred
        float2 v1 = make_float2(rp[l + 64], pp[l + 64]);
        fft128(v0, v1, tc, ts, te);
        *reinterpret_cast<float4*>(&plane[y * PP + f2]) =
            make_float4(v0.x, v0.y, v1.x, v1.y);
    }
    __syncthreads();
    const size_t zb = (size_t)bl * VOL + (size_t)x * NSQ;
#pragma unroll 2
    for (int k = 0; k < 8; ++k) {
        const int z = w * 8 + k;
        float2 v0 = plane[l * PP + z];
        float2 v1 = plane[(l + 64) * PP + z];
        fft128(v0, v1, tc, ts, te);
        *reinterpret_cast<float4*>(&Z[zb + (size_t)z * N + f2]) =
            make_float4(v0.x, v0.y, v1.x, v1.y);
    }
}

// ---------------------------------------------------------------------------
// Exact floor(sqrt(r2)) for integer r2.
// ---------------------------------------------------------------------------
__device__ inline int isqrt_i(int r2) {
    int s = (int)sqrtf((float)r2);
    s -= (s * s > r2);
    s += ((s + 1) * (s + 1) <= r2);
    return s;
}

// ---------------------------------------------------------------------------
// Pass 2 (fused x-FFT + Hermitian shell reduce).
// Block = (batch, z, 16-wide y tile). Loads its tile and the mirror tile
// (-y,-z) for all x (128 B segments), x-FFTs all 32 lines in registers,
// then accumulates full-space weight-1 shell sums: every (y,z) line is the
// primary tile of exactly one block, each point uses its Hermitian partner
// F(-k) = TB[mx][yi]. Mirror-tile reads mostly hit L2/L3 (Z fits in LLC).
// ---------------------------------------------------------------------------
__global__ __launch_bounds__(512, 4) void k_fftx_reduce(const float2* __restrict__ Z,
                                                        float* __restrict__ accum, int b0) {
    const int t = threadIdx.x, l = t & 63, w = t >> 6;   // 8 waves
    const int yt = blockIdx.x & 7;
    const int z  = (blockIdx.x >> 3) & (N - 1);
    const int bl = blockIdx.x >> 10;
    const int fz = z - ((z >= 64) ? N : 0);
    const int minfy = (yt < 4) ? yt * 16 : 113 - yt * 16;   // min |fy| over tile
    if (fz * fz + minfy * minfy >= NSHELL * NSHELL) return; // whole tile >= shell 64

    __shared__ __align__(16) float2 TT[2 * N * TP2];        // TA | TB, 34,816 B
    __shared__ float bins[4 * 193];
    const int NT = N * TP2;

    const int mz = (N - z) & (N - 1);
    const size_t zbA = (size_t)bl * VOL + (size_t)z  * N;
    const size_t zbB = (size_t)bl * VOL + (size_t)mz * N;
#pragma unroll
    for (int k = 0; k < 4; ++k) {
        const int e  = k * 512 + t;          // 2048 points per tile
        const int xx = e >> 4, yi = e & 15;
        const int y  = yt * 16 + yi;
        const int my = (N - y) & (N - 1);
        TT[xx * TP2 + yi]      = Z[zbA + (size_t)xx * NSQ + y];
        TT[NT + xx * TP2 + yi] = Z[zbB + (size_t)xx * NSQ + my];
    }
    for (int i = t; i < 4 * 193; i += 512) bins[i] = 0.f;

    float tc[7], ts[7], te[7];
    mk_tw(l, tc, ts, te);
    const int f2 = (int)(__brev((unsigned)l) >> 26) << 1;
    __syncthreads();

    // x-FFT: 32 lines (16 per tile), 4 per wave; column i is private to its wave.
#pragma unroll
    for (int k = 0; k < 4; ++k) {
        const int idx = w * 4 + k;           // 0..31 (wave-uniform)
        float2* T = TT + (idx >> 4) * NT;
        const int i = idx & 15;
        float2 v0 = T[l * TP2 + i];
        float2 v1 = T[(l + 64) * TP2 + i];
        fft128(v0, v1, tc, ts, te);
        T[f2 * TP2 + i]       = v0;
        T[(f2 + 1) * TP2 + i] = v1;
    }
    __syncthreads();

    // Reduce: thread (x = t&127, ih = t>>7) walks 4 consecutive y's.
    float* mybins = bins + (t & 3) * 193;
    const int x  = t & (N - 1);
    const int ih = t >> 7;                   // 0..3
    const int mx = (N - x) & (N - 1);
    const int fx = x - ((x >= 64) ? N : 0);
    const int fxz = fx * fx + fz * fz;
    float aC = 0.f, aP1 = 0.f, aP2 = 0.f;
    int cs = -1;
#pragma unroll
    for (int j = 0; j < 4; ++j) {
        const int yi = ih * 4 + j;
        const int y  = yt * 16 + yi;
        const int fy = y - ((y >= 64) ? N : 0);
        const int s  = isqrt_i(fxz + fy * fy);
        if (s != cs) {
            if (cs >= 0 && cs < NSHELL) {
                atomicAdd(&mybins[cs * 3 + 0], aC);
                atomicAdd(&mybins[cs * 3 + 1], aP1);
                atomicAdd(&mybins[cs * 3 + 2], aP2);
            }
            cs = s; aC = 0.f; aP1 = 0.f; aP2 = 0.f;
        }
        if (s < NSHELL) {
            const float2 Av = TT[x * TP2 + yi];        // F(k)
            const float2 Bv = TT[NT + mx * TP2 + yi];  // F(-k)
            const float F1x = 0.5f * (Av.x + Bv.x);
            const float F1y = 0.5f * (Av.y - Bv.y);
            const float F2x = 0.5f * (Av.y + Bv.y);
            const float F2y = 0.5f * (Bv.x - Av.x);
            aC  += F1x * F2x + F1y * F2y;
            aP1 += F1x * F1x + F1y * F1y;
            aP2 += F2x * F2x + F2y * F2y;
        }
    }
    if (cs >= 0 && cs < NSHELL) {
        atomicAdd(&mybins[cs * 3 + 0], aC);
        atomicAdd(&mybins[cs * 3 + 1], aP1);
        atomicAdd(&mybins[cs * 3 + 2], aP2);
    }
    __syncthreads();

    float* acc = accum + (size_t)(b0 + bl) * (NSHELL * 3);
    for (int i = t; i < NSHELL * 3; i += 512) {
        const float v = bins[i] + bins[193 + i] + bins[2 * 193 + i] + bins[3 * 193 + i];
        atomicAdd(&acc[i], v);
    }
}

// ---------------------------------------------------------------------------
// Pass 3: FSC + loss. 512 threads = 8 batches x 64 shells.
// ---------------------------------------------------------------------------
__global__ __launch_bounds__(512) void k_final(const float* __restrict__ accum,
                                               float* __restrict__ out) {
    __shared__ float red[8];
    const int tid = threadIdx.x;
    const float* a = accum + (size_t)tid * 3;
    const float fsc = a[0] / (sqrtf(a[1] * a[2]) + 1e-8f);
    float v = fsc * fsc;
#pragma unroll
    for (int off = 32; off > 0; off >>= 1) v += __shfl_down(v, off);
    if ((tid & 63) == 0) red[tid >> 6] = v;
    __syncthreads();
    if (tid == 0) {
        float ssum = 0.f;
#pragma unroll
        for (int i = 0; i < 8; ++i) ssum += red[i];
        out[0] = 1.0f - ssum / 512.0f;
    }
}

extern "C" void kernel_launch(void* const* d_in, const int* in_sizes, int n_in,
                              void* d_out, int out_size, void* d_ws, size_t ws_size,
                              hipStream_t stream) {
    const float* ref  = (const float*)d_in[0];
    const float* pred = (const float*)d_in[1];
    float* out = (float*)d_out;

    char*   ws    = (char*)d_ws;
    float*  accum = (float*)ws;
    float2* Zbuf  = (float2*)(ws + 8192);

    const size_t zbytes = (size_t)VOL * sizeof(float2);
    int cap = 1;
    if (ws_size > 8192) {
        size_t c = (ws_size - 8192) / zbytes;
        cap = (c < 1) ? 1 : (c > BTOT ? BTOT : (int)c);
    }

    hipMemsetAsync(accum, 0, BTOT * NSHELL * 3 * sizeof(float), stream);

    for (int b0 = 0; b0 < BTOT; b0 += cap) {
        const int nb = (BTOT - b0 < cap) ? (BTOT - b0) : cap;
        k_fft_zy<<<nb * 128, 1024, 0, stream>>>(ref, pred, Zbuf, b0);
        k_fftx_reduce<<<nb * 1024, 512, 0, stream>>>(Zbuf, accum, b0);
    }
    k_final<<<1, 512, 0, stream>>>(accum, out);
}